// Round 1
// baseline (397.925 us; speedup 1.0000x reference)
//
#include <hip/hip_runtime.h>
#include <stdint.h>

#define B_    8
#define A_    49104
#define C_    90
#define IMG_  512.0f
#define THR_  0.2f
#define KPRE  1000
#define KOUT  100
#define NCAND 1024   // padded candidate count (power of two)
#define NKEY  2048   // compaction buffer per image

static __device__ __forceinline__ uint32_t f2ord(float f) {
    uint32_t b = __float_as_uint(f);
    return (b & 0x80000000u) ? ~b : (b | 0x80000000u);
}
static __device__ __forceinline__ float ord2f(uint32_t u) {
    uint32_t b = (u & 0x80000000u) ? (u & 0x7FFFFFFFu) : ~u;
    return __uint_as_float(b);
}

// ---------------------------------------------------------------- kernel 1
// per-anchor max/argmax over 90 classes + box decode/clip
__global__ void k_score_decode(const float* __restrict__ cls,
                               const float* __restrict__ loc,
                               const float* __restrict__ anc,
                               uint32_t* __restrict__ scores_u,
                               int* __restrict__ classes,
                               float* __restrict__ boxes) {
    int gid = blockIdx.x * blockDim.x + threadIdx.x;
    if (gid >= B_ * A_) return;

    const float2* p = (const float2*)cls + (size_t)gid * (C_ / 2);
    float best = -1.0f; int bi = 0;
    #pragma unroll 9
    for (int t = 0; t < C_ / 2; ++t) {
        float2 v = p[t];
        if (v.x > best) { best = v.x; bi = 2 * t; }
        if (v.y > best) { best = v.y; bi = 2 * t + 1; }
    }
    float m = (best > THR_) ? best : -1.0f;
    scores_u[gid] = f2ord(m);
    classes[gid]  = bi;

    int a = gid % A_;
    float4 an = ((const float4*)anc)[a];
    float4 l4 = ((const float4*)loc)[gid];
    float ya = (an.x + an.z) * 0.5f;
    float xa = (an.y + an.w) * 0.5f;
    float ha = an.z - an.x;
    float wa = an.w - an.y;
    float h  = expf(l4.z) * ha;
    float w  = expf(l4.w) * wa;
    float yc = l4.x * ha + ya;
    float xc = l4.y * wa + xa;
    float x0 = xc - w * 0.5f, y0 = yc - h * 0.5f;
    float x1 = xc + w * 0.5f, y1 = yc + h * 0.5f;
    float4 bx;
    bx.x = fminf(fmaxf(x0, 0.0f), IMG_);
    bx.y = fminf(fmaxf(y0, 0.0f), IMG_);
    bx.z = fminf(fmaxf(x1, 0.0f), IMG_);
    bx.w = fminf(fmaxf(y1, 0.0f), IMG_);
    ((float4*)boxes)[gid] = bx;
}

// ---------------------------------------------------------------- kernel 2
// per-image MSD radix select of 1000th-largest key + compaction of u>=cutoff
__global__ void k_select(const uint32_t* __restrict__ scores_u,
                         uint64_t* __restrict__ keys) {
    int b = blockIdx.x;
    const uint32_t* su = scores_u + (size_t)b * A_;
    __shared__ uint32_t hist[256];
    __shared__ uint32_t sh_sel, sh_k;
    __shared__ int sh_cnt;

    uint32_t prefix = 0, k = KPRE;
    for (int pass = 0; pass < 4; ++pass) {
        int shift = 24 - pass * 8;
        uint32_t pm = (pass == 0) ? 0u : (0xFFFFFFFFu << (shift + 8));
        for (int i = threadIdx.x; i < 256; i += blockDim.x) hist[i] = 0;
        __syncthreads();
        for (int a = threadIdx.x; a < A_; a += blockDim.x) {
            uint32_t u = su[a];
            if (((u ^ prefix) & pm) == 0)
                atomicAdd(&hist[(u >> shift) & 0xFF], 1u);
        }
        __syncthreads();
        if (threadIdx.x == 0) {
            uint32_t cum = 0, sel = 0, kk = k;
            for (int v = 255; v >= 0; --v) {
                uint32_t h = hist[v];
                if (cum + h >= kk) { sel = (uint32_t)v; kk -= cum; break; }
                cum += h;
            }
            sh_sel = sel; sh_k = kk;
        }
        __syncthreads();
        prefix |= sh_sel << shift;
        k = sh_k;
        __syncthreads();
    }

    uint32_t cutoff = prefix;
    if (threadIdx.x == 0) sh_cnt = 0;
    __syncthreads();
    for (int a = threadIdx.x; a < A_; a += blockDim.x) {
        uint32_t u = su[a];
        if (u >= cutoff) {
            int p = atomicAdd(&sh_cnt, 1);
            if (p < NKEY)
                keys[(size_t)b * NKEY + p] =
                    ((uint64_t)u << 32) | (uint32_t)(~(uint32_t)a);
        }
    }
    __syncthreads();
    int n = sh_cnt; if (n > NKEY) n = NKEY;
    for (int p = n + threadIdx.x; p < NKEY; p += blockDim.x)
        keys[(size_t)b * NKEY + p] = 0ull;
}

// ---------------------------------------------------------------- kernel 3
// bitonic sort 2048 keys desc (value desc, index asc) + emit candidates
__global__ void k_sortcand(const uint64_t* __restrict__ keys,
                           const int* __restrict__ classes,
                           const float* __restrict__ boxes,
                           float* __restrict__ cand_val,
                           int* __restrict__ cand_cls,
                           float* __restrict__ cand_box,
                           int* __restrict__ n_valid) {
    int b = blockIdx.x;
    __shared__ uint64_t s[NKEY];
    __shared__ int s_nv;
    for (int i = threadIdx.x; i < NKEY; i += blockDim.x)
        s[i] = keys[(size_t)b * NKEY + i];
    __syncthreads();

    for (int k = 2; k <= NKEY; k <<= 1) {
        for (int j = k >> 1; j > 0; j >>= 1) {
            for (int i = threadIdx.x; i < NKEY; i += blockDim.x) {
                int ixj = i ^ j;
                if (ixj > i) {
                    uint64_t a = s[i], c = s[ixj];
                    bool up = (i & k) == 0;   // descending overall
                    if (up ? (a < c) : (a > c)) { s[i] = c; s[ixj] = a; }
                }
            }
            __syncthreads();
        }
    }

    if (threadIdx.x == 0) s_nv = 0;
    __syncthreads();
    for (int i = threadIdx.x; i < NCAND; i += blockDim.x) {
        uint64_t kk = s[i];
        uint32_t u = (uint32_t)(kk >> 32);
        int ai; float f;
        if (u == 0u) { f = -1.0f; ai = 0; }
        else         { f = ord2f(u); ai = (int)(~(uint32_t)kk); }
        int ci = b * NCAND + i;
        cand_val[ci] = f;
        cand_cls[ci] = classes[(size_t)b * A_ + ai];
        ((float4*)cand_box)[ci] = ((const float4*)boxes)[(size_t)b * A_ + ai];
        if (f > THR_) atomicAdd(&s_nv, 1);
    }
    __syncthreads();
    if (threadIdx.x == 0) {
        int nv = s_nv; if (nv > KPRE) nv = KPRE;
        n_valid[b] = nv;
    }
}

// ---------------------------------------------------------------- kernel 4
// IoU > 0.2 bitmask matrix: rows [KPRE] x 64 u16 words (1024 cols)
__global__ void k_masks(const float* __restrict__ cand_box,
                        const int* __restrict__ cand_cls,
                        unsigned short* __restrict__ M16) {
    int b = blockIdx.x;
    __shared__ float x1s[NCAND], y1s[NCAND], x2s[NCAND], y2s[NCAND], ars[NCAND];
    for (int i = threadIdx.x; i < NCAND; i += blockDim.x) {
        int ci = b * NCAND + i;
        float4 bx = ((const float4*)cand_box)[ci];
        float off = (float)cand_cls[ci] * (IMG_ + 1.0f);
        float ox1 = bx.x + off, oy1 = bx.y + off;
        float ox2 = bx.z + off, oy2 = bx.w + off;
        x1s[i] = ox1; y1s[i] = oy1; x2s[i] = ox2; y2s[i] = oy2;
        ars[i] = (ox2 - ox1) * (oy2 - oy1);   // area AFTER offset, like the ref
    }
    __syncthreads();

    int row0 = blockIdx.y * 63;               // 16 chunks x 63 rows >= 1000
    for (int item = threadIdx.x; item < 63 * 64; item += blockDim.x) {
        int i = row0 + (item >> 6);
        if (i >= KPRE) continue;
        int w = item & 63;
        float xi1 = x1s[i], yi1 = y1s[i], xi2 = x2s[i], yi2 = y2s[i], ai = ars[i];
        unsigned int m = 0;
        int j0 = w * 16;
        #pragma unroll
        for (int t = 0; t < 16; ++t) {
            int j = j0 + t;
            float xx1 = fmaxf(xi1, x1s[j]);
            float yy1 = fmaxf(yi1, y1s[j]);
            float xx2 = fminf(xi2, x2s[j]);
            float yy2 = fminf(yi2, y2s[j]);
            float iw = xx2 - xx1; iw = iw > 0.0f ? iw : 0.0f;
            float ih = yy2 - yy1; ih = ih > 0.0f ? ih : 0.0f;
            float inter = iw * ih;
            float den = (ai + ars[j]) - inter + 1e-8f;   // ref associativity
            float iou = inter / den;
            m |= (iou > THR_ ? 1u : 0u) << t;
        }
        M16[((size_t)(b * NCAND + i)) * 64 + w] = (unsigned short)m;
    }
}

// ---------------------------------------------------------------- kernel 5
// sequential greedy NMS scan (1 wave/image) + output emit
__global__ void k_nms_out(const unsigned short* __restrict__ M16,
                          const float* __restrict__ cand_val,
                          const int* __restrict__ cand_cls,
                          const float* __restrict__ cand_box,
                          const int* __restrict__ n_valid,
                          float* __restrict__ out) {
    int b = blockIdx.x;
    int lane = threadIdx.x;  // 64
    int nv = n_valid[b]; if (nv > KPRE) nv = KPRE;
    const unsigned short* Mr = M16 + (size_t)b * NCAND * 64;
    __shared__ int kept[KOUT];

    uint32_t S = 0;          // 16 suppression bits per lane
    int cnt = 0;
    uint32_t cur[8], nxt[8];
    #pragma unroll
    for (int t = 0; t < 8; ++t) cur[t] = Mr[(size_t)t * 64 + lane];

    for (int base = 0; base < nv && cnt < KOUT; base += 8) {
        #pragma unroll
        for (int t = 0; t < 8; ++t) {
            int r = base + 8 + t;
            nxt[t] = Mr[(size_t)(r < NCAND ? r : 0) * 64 + lane];
        }
        #pragma unroll
        for (int t = 0; t < 8; ++t) {
            int i = base + t;
            bool inb = (i < nv) && (cnt < KOUT);
            unsigned long long ball =
                __ballot(inb && (((S >> (i & 15)) & 1u) != 0u));
            int sup = (int)((ball >> (i >> 4)) & 1ull);
            if (inb && !sup) {
                S |= cur[t];
                if (lane == 0) kept[cnt] = i;
                cnt++;
            }
        }
        #pragma unroll
        for (int t = 0; t < 8; ++t) cur[t] = nxt[t];
    }
    __syncthreads();

    for (int s_ = lane; s_ < KOUT; s_ += 64) {
        float b0 = 0.0f, b1 = 0.0f, b2 = 1.0f, b3 = 1.0f, sc = 0.0f, lb = -1.0f;
        if (s_ < cnt) {
            int i = kept[s_];
            int ci = b * NCAND + i;
            float4 bx = ((const float4*)cand_box)[ci];
            b0 = bx.x; b1 = bx.y; b2 = bx.z; b3 = bx.w;
            sc = cand_val[ci];
            lb = (float)cand_cls[ci];
        }
        int ob = (b * KOUT + s_) * 4;
        out[ob + 0] = b0; out[ob + 1] = b1; out[ob + 2] = b2; out[ob + 3] = b3;
        out[B_ * KOUT * 4 + b * KOUT + s_] = sc;          // scores
        out[B_ * KOUT * 5 + b * KOUT + s_] = lb;          // labels (as f32)
    }
}

// ----------------------------------------------------------------
extern "C" void kernel_launch(void* const* d_in, const int* in_sizes, int n_in,
                              void* d_out, int out_size, void* d_ws, size_t ws_size,
                              hipStream_t stream) {
    const float* cls = (const float*)d_in[0];
    const float* loc = (const float*)d_in[1];
    const float* anc = (const float*)d_in[2];
    float* out = (float*)d_out;

    char* ws = (char*)d_ws;
    size_t off = 0;
    auto alloc = [&](size_t bytes) -> void* {
        void* p = ws + off;
        off += (bytes + 255) & ~(size_t)255;
        return p;
    };
    uint32_t* scores_u = (uint32_t*)alloc((size_t)B_ * A_ * 4);
    int*      classes  = (int*)     alloc((size_t)B_ * A_ * 4);
    float*    boxes    = (float*)   alloc((size_t)B_ * A_ * 4 * 4);
    uint64_t* keys     = (uint64_t*)alloc((size_t)B_ * NKEY * 8);
    float*    cand_val = (float*)   alloc((size_t)B_ * NCAND * 4);
    int*      cand_cls = (int*)     alloc((size_t)B_ * NCAND * 4);
    float*    cand_box = (float*)   alloc((size_t)B_ * NCAND * 4 * 4);
    int*      n_valid  = (int*)     alloc((size_t)B_ * 4);
    unsigned short* M16 = (unsigned short*)alloc((size_t)B_ * NCAND * 64 * 2);

    int total = B_ * A_;
    k_score_decode<<<(total + 255) / 256, 256, 0, stream>>>(
        cls, loc, anc, scores_u, classes, boxes);
    k_select<<<B_, 1024, 0, stream>>>(scores_u, keys);
    k_sortcand<<<B_, 1024, 0, stream>>>(
        keys, classes, boxes, cand_val, cand_cls, cand_box, n_valid);
    k_masks<<<dim3(B_, 16), 256, 0, stream>>>(cand_box, cand_cls, M16);
    k_nms_out<<<B_, 64, 0, stream>>>(
        M16, cand_val, cand_cls, cand_box, n_valid, out);
}